// Round 8
// baseline (348.173 us; speedup 1.0000x reference)
//
#include <hip/hip_runtime.h>
#include <hip/hip_bf16.h>
#include <hip/hip_fp16.h>

// ScannedRNN (GRU with resets), T=512 B=256 H=INP=256, MI355X gfx950.
//
// Round 8: M=32 batch tiles, 32 time-chunks x 16 steps (256 WGs).
//  - Halves sequential steps (slowest WG ~44 -> ~29) to amortize the ~5K cyc
//    fixed per-step latency found in r7's counters.
//  - Weights: {r/ht0, r/ht1, z/ht0, n/ht0} in 128 AGPRs; {z/ht1, n/ht1} in
//    128 KiB LDS. A-tile 32x256 bf16 double-buffered (32 KiB) -> LDS =
//    163840 B exactly (160 KiB, AITER/HK-proven). lastreset aliased in Ald[1].
//  - gi block layout [t][bt32][wid][lane][g][m][8]: each thread's 6 u16x8
//    are one contiguous 96 B run -> all loads/stores imm-offset folded.
//  - Per-m split of MFMA+gates keeps acc pressure at 24 regs (no spill).
//  - Kept from r7: sigma K-pairing + cvt_pk h-writes, C-in acc init, lgkm-only
//    barrier, 1-step gi prefetch, exact reset lookback, h fp32 in regs.

#define T_LEN 512
#define BATCH 256
#define HID   256
#define CHL   16                    /* steps per chunk */

typedef __attribute__((ext_vector_type(8))) short s16x8;          // 8 bf16
typedef __attribute__((ext_vector_type(8))) unsigned short u16x8; // 8 f16
typedef __attribute__((ext_vector_type(4))) float fx4;            // 4 f32 acc

#define MFMA16 __builtin_amdgcn_mfma_f32_16x16x32_bf16
#define BLKH  24576u                /* halves per (t,bt32) gi block (48 KiB) */
#define TSTRH 196608u               /* 8 blocks per t */

__device__ __forceinline__ unsigned short f2bf(float f) {
  union { float f; unsigned u; } v; v.f = f;
  unsigned r = v.u + 0x7fffu + ((v.u >> 16) & 1u);   // RNE
  return (unsigned short)(r >> 16);
}

__device__ __forceinline__ unsigned cvt_pk_bf16(float lo, float hi) {
  unsigned r;
  asm("v_cvt_pk_bf16_f32 %0, %1, %2" : "=v"(r) : "v"(lo), "v"(hi));
  return r;
}

__device__ __forceinline__ s16x8 pack8(float4 a, float4 b) {   // natural K
  s16x8 f;
  f[0] = (short)f2bf(a.x); f[1] = (short)f2bf(a.y);
  f[2] = (short)f2bf(a.z); f[3] = (short)f2bf(a.w);
  f[4] = (short)f2bf(b.x); f[5] = (short)f2bf(b.y);
  f[6] = (short)f2bf(b.z); f[7] = (short)f2bf(b.w);
  return f;
}

__device__ __forceinline__ s16x8 pack8i(float4 a, float4 b) {  // sigma K
  s16x8 f;
  f[0] = (short)f2bf(a.x); f[1] = (short)f2bf(b.x);
  f[2] = (short)f2bf(a.y); f[3] = (short)f2bf(b.y);
  f[4] = (short)f2bf(a.z); f[5] = (short)f2bf(b.z);
  f[6] = (short)f2bf(a.w); f[7] = (short)f2bf(b.w);
  return f;
}

// wrA[0]=r/ht0  wrA[1]=r/ht1  wrA[2]=z/ht0  wrA[3]=n/ht0   (128 regs -> AGPR)
// Wlds 128 KiB: set0 = z/ht1 (64K), set1 = n/ht1 (64K); line [set][wv][s8][lane].
template<bool SIGMA>
__device__ __forceinline__ void load_weights(const float* __restrict__ W,
                                             s16x8 (&wrA)[4][8], char* Wlds,
                                             int tid, int wid, int col, int kgrp) {
  const int rowbase[4] = {0, 16, 256, 512};
#pragma unroll
  for (int k = 0; k < 4; ++k) {
    int row = rowbase[k] + wid * 32 + col;
#pragma unroll
    for (int s8 = 0; s8 < 8; ++s8) {
      if (SIGMA) {
        const float* pa = W + row * 256 + s8 * 32 + kgrp * 4;
        wrA[k][s8] = pack8i(*(const float4*)pa, *(const float4*)(pa + 16));
      } else {
        const float* pa = W + row * 256 + s8 * 32 + kgrp * 8;
        wrA[k][s8] = pack8(*(const float4*)pa, *(const float4*)(pa + 4));
      }
    }
  }
#pragma unroll
  for (int q = 0; q < 16; ++q) {
    int li = tid + q * 512;             // 8192 lines of 16 B
    int set = li >> 12, wv = (li >> 9) & 7, s8 = (li >> 6) & 7, l = li & 63;
    int row = (set ? 512 : 256) + wv * 32 + 16 + (l & 15);
    s16x8 line;
    if (SIGMA) {
      const float* pa = W + row * 256 + s8 * 32 + (l >> 4) * 4;
      line = pack8i(*(const float4*)pa, *(const float4*)(pa + 16));
    } else {
      const float* pa = W + row * 256 + s8 * 32 + (l >> 4) * 8;
      line = pack8(*(const float4*)pa, *(const float4*)(pa + 4));
    }
    *(s16x8*)(Wlds + li * 16) = line;
  }
}

__device__ __forceinline__ void soft_barrier() {
  asm volatile("s_waitcnt lgkmcnt(0)" ::: "memory");
  __builtin_amdgcn_s_barrier();
  __builtin_amdgcn_sched_barrier(0);
  asm volatile("" ::: "memory");
}

// ---------------- Kernel A: input projection -> gi (f16) ----------------
__global__ __launch_bounds__(512, 2) void gi_proj_kernel(
    const float* __restrict__ X, const float* __restrict__ w_ih,
    const float* __restrict__ b_ih, const float* __restrict__ b_hh,
    __half* __restrict__ gi) {
  __shared__ __align__(16) char Wlds[131072];
  __shared__ __align__(16) char Ald[2][16384];   // 32x256 bf16, swizzled, dbuf

  const int tid = threadIdx.x;
  const int wid = tid >> 6, lane = tid & 63;
  const int col = lane & 15, kgrp = lane >> 4;

  s16x8 wrA[4][8];
  load_weights<false>(w_ih, wrA, Wlds, tid, wid, col, kgrp);

  float bias[2][3];
#pragma unroll
  for (int ht = 0; ht < 2; ++ht) {
    int gb = wid * 32 + ht * 16 + col;
    bias[ht][0] = b_ih[gb]       + b_hh[gb];        // fold b_hh for r
    bias[ht][1] = b_ih[256 + gb] + b_hh[256 + gb];  // fold b_hh for z
    bias[ht][2] = b_ih[512 + gb];                   // n: b_hh inside r*( )
  }

  const int srow = tid >> 4, skb = tid & 15;   // 32 rows x 16 col-blocks
  const unsigned sx = (unsigned)(srow & 7) << 4;
  const unsigned sb0 = (unsigned)(srow * 512 + skb * 32);

  float4 xc0, xc1, xc2, xc3;
  {
    const float* xp = X + (size_t)(blockIdx.x * 32 + srow) * 256 + skb * 16;
    xc0 = *(const float4*)(xp); xc1 = *(const float4*)(xp + 4);
    xc2 = *(const float4*)(xp + 8); xc3 = *(const float4*)(xp + 12);
  }

  int parity = 0;
  for (int c32 = blockIdx.x; c32 < 4096; c32 += 256) {
    char* ab = Ald[parity];
    {
      uint4 u0, u1;
      u0.x = cvt_pk_bf16(xc0.x, xc0.y); u0.y = cvt_pk_bf16(xc0.z, xc0.w);
      u0.z = cvt_pk_bf16(xc1.x, xc1.y); u0.w = cvt_pk_bf16(xc1.z, xc1.w);
      u1.x = cvt_pk_bf16(xc2.x, xc2.y); u1.y = cvt_pk_bf16(xc2.z, xc2.w);
      u1.z = cvt_pk_bf16(xc3.x, xc3.y); u1.w = cvt_pk_bf16(xc3.z, xc3.w);
      *(uint4*)(ab + (sb0 ^ sx)) = u0;
      *(uint4*)(ab + ((sb0 + 16) ^ sx)) = u1;
    }
    int nc = c32 + 256;
    if (nc < 4096) {
      const float* xp = X + (size_t)(nc * 32 + srow) * 256 + skb * 16;
      xc0 = *(const float4*)(xp); xc1 = *(const float4*)(xp + 4);
      xc2 = *(const float4*)(xp + 8); xc3 = *(const float4*)(xp + 12);
    }
    soft_barrier();   // stage visible; X prefetch + gi stores stay in flight

    __half* gb = gi + (size_t)c32 * BLKH + (unsigned)(wid * 64 + lane) * 48;
#pragma unroll
    for (int m = 0; m < 2; ++m) {
      fx4 aR0, aR1, aZ0, aZ1, aN0, aN1;
#pragma unroll
      for (int j = 0; j < 4; ++j) {
        aR0[j] = bias[0][0]; aR1[j] = bias[1][0];
        aZ0[j] = bias[0][1]; aZ1[j] = bias[1][1];
        aN0[j] = bias[0][2]; aN1[j] = bias[1][2];
      }
#pragma unroll
      for (int s8 = 0; s8 < 8; ++s8) {
        unsigned aoff = ((unsigned)((m * 16 + col) * 512 + s8 * 64 + kgrp * 16)) ^
                        ((unsigned)(col & 7) << 4);
        s16x8 af  = *(const s16x8*)(ab + aoff);
        s16x8 wz1 = *(const s16x8*)(Wlds + (wid * 512 + s8 * 64 + lane) * 16);
        s16x8 wn1 = *(const s16x8*)(Wlds + 65536 + (wid * 512 + s8 * 64 + lane) * 16);
        aR0 = MFMA16(af, wrA[0][s8], aR0, 0, 0, 0);
        aR1 = MFMA16(af, wrA[1][s8], aR1, 0, 0, 0);
        aZ0 = MFMA16(af, wrA[2][s8], aZ0, 0, 0, 0);
        aZ1 = MFMA16(af, wz1, aZ1, 0, 0, 0);
        aN0 = MFMA16(af, wrA[3][s8], aN0, 0, 0, 0);
        aN1 = MFMA16(af, wn1, aN1, 0, 0, 0);
      }
      u16x8 oR, oZ, oN;
#pragma unroll
      for (int j = 0; j < 4; ++j) {
        oR[j] = __half_as_ushort(__float2half(aR0[j]));
        oR[4 + j] = __half_as_ushort(__float2half(aR1[j]));
        oZ[j] = __half_as_ushort(__float2half(aZ0[j]));
        oZ[4 + j] = __half_as_ushort(__float2half(aZ1[j]));
        oN[j] = __half_as_ushort(__float2half(aN0[j]));
        oN[4 + j] = __half_as_ushort(__float2half(aN1[j]));
      }
      *(u16x8*)(gb + m * 8) = oR;
      *(u16x8*)(gb + 16 + m * 8) = oZ;
      *(u16x8*)(gb + 32 + m * 8) = oN;
    }
    parity ^= 1;
  }
}

// ---------------- Kernel B: chunked GRU scan (M=32) ----------------
__global__ __launch_bounds__(512, 2) void gru_scan_kernel(
    const float* __restrict__ carry, const __half* __restrict__ gi,
    const int* __restrict__ resets, const float* __restrict__ w_hh,
    const float* __restrict__ b_hh, float* __restrict__ out) {
  __shared__ __align__(16) char Wlds[131072];
  __shared__ __align__(16) char Ald[2][16384];   // h bf16 A-tile (sigma), dbuf
  int* lastreset = (int*)(Ald[1]);               // aliased (prologue only)

  const int tid = threadIdx.x;
  const int wid = tid >> 6, lane = tid & 63;
  const int col = lane & 15, kgrp = lane >> 4;
  const int bid = blockIdx.x;
  const int bt = bid & 7, c = bid >> 3;
  const int b0 = bt * 32, t0 = c * CHL, t1 = t0 + CHL;
  const int hid0 = wid * 32 + col;

  s16x8 wrA[4][8];
  load_weights<true>(w_hh, wrA, Wlds, tid, wid, col, kgrp);
  const float bhhn0 = b_hh[512 + hid0], bhhn1 = b_hh[512 + hid0 + 16];

  // ---- exact scan start: min over 32-b tile of (last reset < t0) ----
  int s, useCarry;
  if (c == 0) {
    s = 0; useCarry = 1;
  } else {
    if (tid < 32) lastreset[tid] = -1;
    for (int base = t0 - 16;; base -= 16) {   // 512 thr: 16 t x 32 b per pass
      __syncthreads();
      int tt = base + (tid >> 5);
      if (tt >= 0 && tt < t0) {
        if (resets[tt * BATCH + b0 + (tid & 31)] != 0)
          atomicMax(&lastreset[tid & 31], tt);
      }
      __syncthreads();
      int mn = t0, all = 1;
#pragma unroll
      for (int i = 0; i < 32; ++i) {
        int v = lastreset[i];
        all &= (v >= 0) ? 1 : 0;
        mn = min(mn, v < 0 ? t0 : v);
      }
      if (all) { s = mn; useCarry = 0; break; }
      if (base <= 0) { s = 0; useCarry = 1; break; }
    }
    __syncthreads();   // lastreset reads done before Ald[1] is reused
  }

  // ---- init state at t=s into Ald[0] (sigma pairs (hid,hid+16)) ----
  {
    int row = tid >> 4, kblk = tid & 15;
    int rst = resets[s * BATCH + b0 + row];
    float4 va0 = {0.f, 0.f, 0.f, 0.f}, va1 = va0, vb0 = va0, vb1 = va0;
    if (useCarry && !rst) {
      const float* cp = carry + (size_t)(b0 + row) * HID + (kblk >> 1) * 32 + (kblk & 1) * 8;
      va0 = *(const float4*)(cp);      va1 = *(const float4*)(cp + 4);
      vb0 = *(const float4*)(cp + 16); vb1 = *(const float4*)(cp + 20);
    }
    uint4 u0, u1;
    u0.x = cvt_pk_bf16(va0.x, vb0.x); u0.y = cvt_pk_bf16(va0.y, vb0.y);
    u0.z = cvt_pk_bf16(va0.z, vb0.z); u0.w = cvt_pk_bf16(va0.w, vb0.w);
    u1.x = cvt_pk_bf16(va1.x, vb1.x); u1.y = cvt_pk_bf16(va1.y, vb1.y);
    u1.z = cvt_pk_bf16(va1.z, vb1.z); u1.w = cvt_pk_bf16(va1.w, vb1.w);
    unsigned sx = (unsigned)(row & 7) << 4;
    unsigned sb0 = (unsigned)(row * 512 + kblk * 32);
    *(uint4*)(Ald[0] + (sb0 ^ sx)) = u0;
    *(uint4*)(Ald[0] + ((sb0 + 16) ^ sx)) = u1;
  }
  float hprev[2][2][4];
#pragma unroll
  for (int m = 0; m < 2; ++m)
#pragma unroll
    for (int j = 0; j < 4; ++j) {
      int b = b0 + m * 16 + kgrp * 4 + j;
      int rst = resets[s * BATCH + b];
      float h0 = 0.f, h1 = 0.f;
      if (useCarry && !rst) {
        h0 = carry[(size_t)b * HID + hid0];
        h1 = carry[(size_t)b * HID + hid0 + 16];
      }
      hprev[m][0][j] = h0; hprev[m][1][j] = h1;
    }

  // ---- prologue loads: gi(s) + resets(s+1) ----
  const __half* gb = gi + (size_t)(s * 8 + bt) * BLKH + (unsigned)(wid * 64 + lane) * 48;
  u16x8 gC[3][2];
#pragma unroll
  for (int g = 0; g < 3; ++g)
#pragma unroll
    for (int m = 0; m < 2; ++m)
      gC[g][m] = *(const u16x8*)(gb + g * 16 + m * 8);
  int4 rnC[2];
  {
    int tn = (s + 1 < T_LEN) ? s + 1 : T_LEN - 1;
#pragma unroll
    for (int m = 0; m < 2; ++m)
      rnC[m] = *(const int4*)(resets + (size_t)tn * BATCH + b0 + m * 16 + kgrp * 4);
  }
  float* opc = out + 65536 + ((size_t)s * BATCH + b0 + kgrp * 4) * HID + hid0;
  __syncthreads();

  // ---- pipelined scan ----
  for (int t = s; t < t1; ++t) {
    const __half* gq = gb + ((t + 1 < t1) ? TSTRH : 0u);
    u16x8 gN[3][2];
#pragma unroll
    for (int g = 0; g < 3; ++g)
#pragma unroll
      for (int m = 0; m < 2; ++m)
        gN[g][m] = *(const u16x8*)(gq + g * 16 + m * 8);
    int4 rnN[2];
    {
      int tn = (t + 2 < T_LEN) ? t + 2 : T_LEN - 1;
#pragma unroll
      for (int m = 0; m < 2; ++m)
        rnN[m] = *(const int4*)(resets + (size_t)tn * BATCH + b0 + m * 16 + kgrp * 4);
    }

    const char* ab = Ald[(t - s) & 1];
    char* aw = (char*)Ald[((t - s) & 1) ^ 1];
    const bool lastT = (t + 1 >= T_LEN);

#pragma unroll
    for (int m = 0; m < 2; ++m) {
      fx4 aR0, aR1, aZ0, aZ1, aN0, aN1;
#pragma unroll
      for (int j = 0; j < 4; ++j) {
        aR0[j] = __half2float(__ushort_as_half(gC[0][m][j]));
        aR1[j] = __half2float(__ushort_as_half(gC[0][m][4 + j]));
        aZ0[j] = __half2float(__ushort_as_half(gC[1][m][j]));
        aZ1[j] = __half2float(__ushort_as_half(gC[1][m][4 + j]));
        aN0[j] = bhhn0;
        aN1[j] = bhhn1;
      }
#pragma unroll
      for (int s8 = 0; s8 < 8; ++s8) {
        unsigned aoff = ((unsigned)((m * 16 + col) * 512 + s8 * 64 + kgrp * 16)) ^
                        ((unsigned)(col & 7) << 4);
        s16x8 af  = *(const s16x8*)(ab + aoff);
        s16x8 wz1 = *(const s16x8*)(Wlds + (wid * 512 + s8 * 64 + lane) * 16);
        s16x8 wn1 = *(const s16x8*)(Wlds + 65536 + (wid * 512 + s8 * 64 + lane) * 16);
        aR0 = MFMA16(af, wrA[0][s8], aR0, 0, 0, 0);
        aR1 = MFMA16(af, wrA[1][s8], aR1, 0, 0, 0);
        aZ0 = MFMA16(af, wrA[2][s8], aZ0, 0, 0, 0);
        aZ1 = MFMA16(af, wz1, aZ1, 0, 0, 0);
        aN0 = MFMA16(af, wrA[3][s8], aN0, 0, 0, 0);
        aN1 = MFMA16(af, wn1, aN1, 0, 0, 0);
      }

      int4 rm = rnC[m];
#pragma unroll
      for (int j = 0; j < 4; ++j) {
        int b = m * 16 + kgrp * 4 + j;          // row within 32-b tile
        int rj = (j == 0) ? rm.x : (j == 1) ? rm.y : (j == 2) ? rm.z : rm.w;
        if (lastT) rj = 0;

        float r0 = __builtin_amdgcn_rcpf(1.f + __expf(-aR0[j]));
        float z0 = __builtin_amdgcn_rcpf(1.f + __expf(-aZ0[j]));
        float pn0 = __half2float(__ushort_as_half(gC[2][m][j])) + r0 * aN0[j];
        float n0 = 1.f - 2.f * __builtin_amdgcn_rcpf(1.f + __expf(2.f * pn0));
        float h0 = (1.f - z0) * n0 + z0 * hprev[m][0][j];

        float r1 = __builtin_amdgcn_rcpf(1.f + __expf(-aR1[j]));
        float z1 = __builtin_amdgcn_rcpf(1.f + __expf(-aZ1[j]));
        float pn1 = __half2float(__ushort_as_half(gC[2][m][4 + j])) + r1 * aN1[j];
        float n1 = 1.f - 2.f * __builtin_amdgcn_rcpf(1.f + __expf(2.f * pn1));
        float h1 = (1.f - z1) * n1 + z1 * hprev[m][1][j];

        __builtin_nontemporal_store(h0, opc + m * 4096 + j * HID);
        __builtin_nontemporal_store(h1, opc + m * 4096 + j * HID + 16);

        float hk0 = rj ? 0.f : h0;              // pre-apply reset[t+1]
        float hk1 = rj ? 0.f : h1;
        hprev[m][0][j] = hk0; hprev[m][1][j] = hk1;

        unsigned hw = cvt_pk_bf16(hk0, hk1);
        unsigned hoff = ((unsigned)(b * 512 + wid * 64 + col * 4)) ^
                        ((unsigned)(b & 7) << 4);
        *(unsigned*)(aw + hoff) = hw;
      }
    }

#pragma unroll
    for (int g = 0; g < 3; ++g)
#pragma unroll
      for (int m = 0; m < 2; ++m)
        gC[g][m] = gN[g][m];
    rnC[0] = rnN[0]; rnC[1] = rnN[1];
    gb = gq;
    opc += 65536;
    soft_barrier();   // lgkm drain only; gi prefetch + out stores in flight
  }

  if (c == 31) {       // h_final = h after t=511 (reset guarded off)
#pragma unroll
    for (int m = 0; m < 2; ++m)
#pragma unroll
      for (int j = 0; j < 4; ++j) {
        int b = b0 + m * 16 + kgrp * 4 + j;
        out[(size_t)b * HID + hid0] = hprev[m][0][j];
        out[(size_t)b * HID + hid0 + 16] = hprev[m][1][j];
      }
  }
}

extern "C" void kernel_launch(void* const* d_in, const int* in_sizes, int n_in,
                              void* d_out, int out_size, void* d_ws, size_t ws_size,
                              hipStream_t stream) {
  const float* carry = (const float*)d_in[0];
  const float* X     = (const float*)d_in[1];
  const int*   rsts  = (const int*)d_in[2];
  const float* w_ih  = (const float*)d_in[3];
  const float* w_hh  = (const float*)d_in[4];
  const float* b_ih  = (const float*)d_in[5];
  const float* b_hh  = (const float*)d_in[6];
  float* out = (float*)d_out;

  const size_t gi_bytes = (size_t)T_LEN * BATCH * 3 * HID * sizeof(__half);  // 192 MiB
  if (ws_size < gi_bytes) return;
  __half* gi = (__half*)d_ws;

  gi_proj_kernel<<<256, 512, 0, stream>>>(X, w_ih, b_ih, b_hh, gi);
  gru_scan_kernel<<<256, 512, 0, stream>>>(carry, gi, rsts, w_hh, b_hh, out);
}

// Round 9
// 308.839 us; speedup vs baseline: 1.1274x; 1.1274x over previous
//
#include <hip/hip_runtime.h>
#include <hip/hip_bf16.h>
#include <hip/hip_fp16.h>

// ScannedRNN (GRU with resets), T=512 B=256 H=INP=256, MI355X gfx950.
//
// Round 9: r8's M=32 structure with a register diet (the r8 spill was the
// 96-reg gi double-buffer) + exp2-folded activations.
//  - Scan: 32 time-chunks x 8 batch-tiles(32) = 256 WGs. Per step: load gi
//    (single-buffered, L2-resident) right after the barrier; two m-phases of
//    {8 af + 16 w2 LDS reads, 48 MFMA, gates, stores, h-writes}; ONE
//    lgkm-only barrier.
//  - Weights {r0,r1,z0,n0} in 128 AGPRs; {z1,n1} in 128 KiB LDS; A-tile
//    32x256 bf16 dbuf (32 KiB) -> LDS exactly 160 KiB. lastreset aliased.
//  - exp2 folding: r,z rows/biases pre-scaled by log2(e), n rows/biases by
//    2*log2(e) -> sigma(x)=rcp(1+exp2(-x)), tanh via 1-2*rcp(1+exp2(pn')).
//  - sigma K-pairing: h written as (hid,hid+16) pairs via v_cvt_pk_bf16_f32.
//  - gi f16 blocks [t][bt32][wid][lane][g][m][8] (WG-private, contiguous 96B
//    per thread), written by proj with M=32 tiles (r8 proj, + scaling).

#define T_LEN 512
#define BATCH 256
#define HID   256
#define CHL   16                    /* steps per chunk */

#define LOG2E     1.4426950408889634f
#define TWO_LOG2E 2.8853900817779268f

typedef __attribute__((ext_vector_type(8))) short s16x8;          // 8 bf16
typedef __attribute__((ext_vector_type(8))) unsigned short u16x8; // 8 f16
typedef __attribute__((ext_vector_type(4))) float fx4;            // 4 f32 acc

#define MFMA16 __builtin_amdgcn_mfma_f32_16x16x32_bf16
#define BLKH  24576u                /* halves per (t,bt32) gi block (48 KiB) */
#define TSTRH 196608u               /* 8 blocks per t */

__device__ __forceinline__ unsigned short f2bf(float f) {
  union { float f; unsigned u; } v; v.f = f;
  unsigned r = v.u + 0x7fffu + ((v.u >> 16) & 1u);   // RNE
  return (unsigned short)(r >> 16);
}

__device__ __forceinline__ unsigned cvt_pk_bf16(float lo, float hi) {
  unsigned r;
  asm("v_cvt_pk_bf16_f32 %0, %1, %2" : "=v"(r) : "v"(lo), "v"(hi));
  return r;
}

__device__ __forceinline__ s16x8 pack8(float4 a, float4 b, float s) {  // natural K
  s16x8 f;
  f[0] = (short)f2bf(a.x * s); f[1] = (short)f2bf(a.y * s);
  f[2] = (short)f2bf(a.z * s); f[3] = (short)f2bf(a.w * s);
  f[4] = (short)f2bf(b.x * s); f[5] = (short)f2bf(b.y * s);
  f[6] = (short)f2bf(b.z * s); f[7] = (short)f2bf(b.w * s);
  return f;
}

__device__ __forceinline__ s16x8 pack8i(float4 a, float4 b, float s) { // sigma K
  s16x8 f;
  f[0] = (short)f2bf(a.x * s); f[1] = (short)f2bf(b.x * s);
  f[2] = (short)f2bf(a.y * s); f[3] = (short)f2bf(b.y * s);
  f[4] = (short)f2bf(a.z * s); f[5] = (short)f2bf(b.z * s);
  f[6] = (short)f2bf(a.w * s); f[7] = (short)f2bf(b.w * s);
  return f;
}

// wrA[0]=r/ht0  wrA[1]=r/ht1  wrA[2]=z/ht0  wrA[3]=n/ht0   (128 regs -> AGPR)
// Wlds 128 KiB: set0 = z/ht1 (64K), set1 = n/ht1 (64K); line [set][wv][s8][lane].
// All weights pre-scaled: r,z rows * LOG2E ; n rows * 2*LOG2E.
template<bool SIGMA>
__device__ __forceinline__ void load_weights(const float* __restrict__ W,
                                             s16x8 (&wrA)[4][8], char* Wlds,
                                             int tid, int wid, int col, int kgrp) {
  const int rowbase[4] = {0, 16, 256, 512};
  const float scl[4] = {LOG2E, LOG2E, LOG2E, TWO_LOG2E};
#pragma unroll
  for (int k = 0; k < 4; ++k) {
    int row = rowbase[k] + wid * 32 + col;
#pragma unroll
    for (int s8 = 0; s8 < 8; ++s8) {
      if (SIGMA) {
        const float* pa = W + row * 256 + s8 * 32 + kgrp * 4;
        wrA[k][s8] = pack8i(*(const float4*)pa, *(const float4*)(pa + 16), scl[k]);
      } else {
        const float* pa = W + row * 256 + s8 * 32 + kgrp * 8;
        wrA[k][s8] = pack8(*(const float4*)pa, *(const float4*)(pa + 4), scl[k]);
      }
    }
  }
#pragma unroll
  for (int q = 0; q < 16; ++q) {
    int li = tid + q * 512;             // 8192 lines of 16 B
    int set = li >> 12, wv = (li >> 9) & 7, s8 = (li >> 6) & 7, l = li & 63;
    int row = (set ? 512 : 256) + wv * 32 + 16 + (l & 15);
    float s = set ? TWO_LOG2E : LOG2E;
    s16x8 line;
    if (SIGMA) {
      const float* pa = W + row * 256 + s8 * 32 + (l >> 4) * 4;
      line = pack8i(*(const float4*)pa, *(const float4*)(pa + 16), s);
    } else {
      const float* pa = W + row * 256 + s8 * 32 + (l >> 4) * 8;
      line = pack8(*(const float4*)pa, *(const float4*)(pa + 4), s);
    }
    *(s16x8*)(Wlds + li * 16) = line;
  }
}

__device__ __forceinline__ void soft_barrier() {
  asm volatile("s_waitcnt lgkmcnt(0)" ::: "memory");
  __builtin_amdgcn_s_barrier();
  __builtin_amdgcn_sched_barrier(0);
  asm volatile("" ::: "memory");
}

// ---------------- Kernel A: input projection -> gi (f16, pre-scaled) ------
__global__ __launch_bounds__(512, 2) void gi_proj_kernel(
    const float* __restrict__ X, const float* __restrict__ w_ih,
    const float* __restrict__ b_ih, const float* __restrict__ b_hh,
    __half* __restrict__ gi) {
  __shared__ __align__(16) char Wlds[131072];
  __shared__ __align__(16) char Ald[2][16384];   // 32x256 bf16, swizzled, dbuf

  const int tid = threadIdx.x;
  const int wid = tid >> 6, lane = tid & 63;
  const int col = lane & 15, kgrp = lane >> 4;

  s16x8 wrA[4][8];
  load_weights<false>(w_ih, wrA, Wlds, tid, wid, col, kgrp);

  float bias[2][3];
#pragma unroll
  for (int ht = 0; ht < 2; ++ht) {
    int gb = wid * 32 + ht * 16 + col;
    bias[ht][0] = (b_ih[gb]       + b_hh[gb])       * LOG2E;   // r (b_hh folded)
    bias[ht][1] = (b_ih[256 + gb] + b_hh[256 + gb]) * LOG2E;   // z (b_hh folded)
    bias[ht][2] = b_ih[512 + gb] * TWO_LOG2E;                  // n (b_hh in scan)
  }

  const int srow = tid >> 4, skb = tid & 15;   // 32 rows x 16 col-blocks
  const unsigned sx = (unsigned)(srow & 7) << 4;
  const unsigned sb0 = (unsigned)(srow * 512 + skb * 32);

  float4 xc0, xc1, xc2, xc3;
  {
    const float* xp = X + (size_t)(blockIdx.x * 32 + srow) * 256 + skb * 16;
    xc0 = *(const float4*)(xp); xc1 = *(const float4*)(xp + 4);
    xc2 = *(const float4*)(xp + 8); xc3 = *(const float4*)(xp + 12);
  }

  int parity = 0;
  for (int c32 = blockIdx.x; c32 < 4096; c32 += 256) {
    char* ab = Ald[parity];
    {
      uint4 u0, u1;
      u0.x = cvt_pk_bf16(xc0.x, xc0.y); u0.y = cvt_pk_bf16(xc0.z, xc0.w);
      u0.z = cvt_pk_bf16(xc1.x, xc1.y); u0.w = cvt_pk_bf16(xc1.z, xc1.w);
      u1.x = cvt_pk_bf16(xc2.x, xc2.y); u1.y = cvt_pk_bf16(xc2.z, xc2.w);
      u1.z = cvt_pk_bf16(xc3.x, xc3.y); u1.w = cvt_pk_bf16(xc3.z, xc3.w);
      *(uint4*)(ab + (sb0 ^ sx)) = u0;
      *(uint4*)(ab + ((sb0 + 16) ^ sx)) = u1;
    }
    int nc = c32 + 256;
    if (nc < 4096) {
      const float* xp = X + (size_t)(nc * 32 + srow) * 256 + skb * 16;
      xc0 = *(const float4*)(xp); xc1 = *(const float4*)(xp + 4);
      xc2 = *(const float4*)(xp + 8); xc3 = *(const float4*)(xp + 12);
    }
    soft_barrier();   // stage visible; X prefetch + gi stores stay in flight

    __half* gb = gi + (size_t)c32 * BLKH + (unsigned)(wid * 64 + lane) * 48;
#pragma unroll
    for (int m = 0; m < 2; ++m) {
      fx4 aR0, aR1, aZ0, aZ1, aN0, aN1;
#pragma unroll
      for (int j = 0; j < 4; ++j) {
        aR0[j] = bias[0][0]; aR1[j] = bias[1][0];
        aZ0[j] = bias[0][1]; aZ1[j] = bias[1][1];
        aN0[j] = bias[0][2]; aN1[j] = bias[1][2];
      }
#pragma unroll
      for (int s8 = 0; s8 < 8; ++s8) {
        unsigned aoff = ((unsigned)((m * 16 + col) * 512 + s8 * 64 + kgrp * 16)) ^
                        ((unsigned)(col & 7) << 4);
        s16x8 af  = *(const s16x8*)(ab + aoff);
        s16x8 wz1 = *(const s16x8*)(Wlds + (wid * 512 + s8 * 64 + lane) * 16);
        s16x8 wn1 = *(const s16x8*)(Wlds + 65536 + (wid * 512 + s8 * 64 + lane) * 16);
        aR0 = MFMA16(af, wrA[0][s8], aR0, 0, 0, 0);
        aR1 = MFMA16(af, wrA[1][s8], aR1, 0, 0, 0);
        aZ0 = MFMA16(af, wrA[2][s8], aZ0, 0, 0, 0);
        aZ1 = MFMA16(af, wz1, aZ1, 0, 0, 0);
        aN0 = MFMA16(af, wrA[3][s8], aN0, 0, 0, 0);
        aN1 = MFMA16(af, wn1, aN1, 0, 0, 0);
      }
      u16x8 oR, oZ, oN;
#pragma unroll
      for (int j = 0; j < 4; ++j) {
        oR[j] = __half_as_ushort(__float2half(aR0[j]));
        oR[4 + j] = __half_as_ushort(__float2half(aR1[j]));
        oZ[j] = __half_as_ushort(__float2half(aZ0[j]));
        oZ[4 + j] = __half_as_ushort(__float2half(aZ1[j]));
        oN[j] = __half_as_ushort(__float2half(aN0[j]));
        oN[4 + j] = __half_as_ushort(__float2half(aN1[j]));
      }
      *(u16x8*)(gb + m * 8) = oR;
      *(u16x8*)(gb + 16 + m * 8) = oZ;
      *(u16x8*)(gb + 32 + m * 8) = oN;
    }
    parity ^= 1;
  }
}

// ---------------- Kernel B: chunked GRU scan (M=32) ----------------
__global__ __launch_bounds__(512, 2) void gru_scan_kernel(
    const float* __restrict__ carry, const __half* __restrict__ gi,
    const int* __restrict__ resets, const float* __restrict__ w_hh,
    const float* __restrict__ b_hh, float* __restrict__ out) {
  __shared__ __align__(16) char Wlds[131072];
  __shared__ __align__(16) char Ald[2][16384];   // h bf16 A-tile (sigma), dbuf
  int* lastreset = (int*)(Ald[1]);               // aliased (prologue only)

  const int tid = threadIdx.x;
  const int wid = tid >> 6, lane = tid & 63;
  const int col = lane & 15, kgrp = lane >> 4;
  const int bid = blockIdx.x;
  const int bt = bid & 7, c = bid >> 3;
  const int b0 = bt * 32, t0 = c * CHL, t1 = t0 + CHL;
  const int hid0 = wid * 32 + col;

  s16x8 wrA[4][8];
  load_weights<true>(w_hh, wrA, Wlds, tid, wid, col, kgrp);
  const float bhhn0 = b_hh[512 + hid0] * TWO_LOG2E;
  const float bhhn1 = b_hh[512 + hid0 + 16] * TWO_LOG2E;

  // ---- exact scan start: min over 32-b tile of (last reset < t0) ----
  int s, useCarry;
  if (c == 0) {
    s = 0; useCarry = 1;
  } else {
    if (tid < 32) lastreset[tid] = -1;
    for (int base = t0 - 16;; base -= 16) {   // 512 thr: 16 t x 32 b per pass
      __syncthreads();
      int tt = base + (tid >> 5);
      if (tt >= 0 && tt < t0) {
        if (resets[tt * BATCH + b0 + (tid & 31)] != 0)
          atomicMax(&lastreset[tid & 31], tt);
      }
      __syncthreads();
      int mn = t0, all = 1;
#pragma unroll
      for (int i = 0; i < 32; ++i) {
        int v = lastreset[i];
        all &= (v >= 0) ? 1 : 0;
        mn = min(mn, v < 0 ? t0 : v);
      }
      if (all) { s = mn; useCarry = 0; break; }
      if (base <= 0) { s = 0; useCarry = 1; break; }
    }
    __syncthreads();   // lastreset reads done before Ald[1] is reused
  }

  // ---- init state at t=s into Ald[0] (sigma pairs (hid,hid+16)) ----
  {
    int row = tid >> 4, kblk = tid & 15;
    int rst = resets[s * BATCH + b0 + row];
    float4 va0 = {0.f, 0.f, 0.f, 0.f}, va1 = va0, vb0 = va0, vb1 = va0;
    if (useCarry && !rst) {
      const float* cp = carry + (size_t)(b0 + row) * HID + (kblk >> 1) * 32 + (kblk & 1) * 8;
      va0 = *(const float4*)(cp);      va1 = *(const float4*)(cp + 4);
      vb0 = *(const float4*)(cp + 16); vb1 = *(const float4*)(cp + 20);
    }
    uint4 u0, u1;
    u0.x = cvt_pk_bf16(va0.x, vb0.x); u0.y = cvt_pk_bf16(va0.y, vb0.y);
    u0.z = cvt_pk_bf16(va0.z, vb0.z); u0.w = cvt_pk_bf16(va0.w, vb0.w);
    u1.x = cvt_pk_bf16(va1.x, vb1.x); u1.y = cvt_pk_bf16(va1.y, vb1.y);
    u1.z = cvt_pk_bf16(va1.z, vb1.z); u1.w = cvt_pk_bf16(va1.w, vb1.w);
    unsigned sx = (unsigned)(row & 7) << 4;
    unsigned sb0 = (unsigned)(row * 512 + kblk * 32);
    *(uint4*)(Ald[0] + (sb0 ^ sx)) = u0;
    *(uint4*)(Ald[0] + ((sb0 + 16) ^ sx)) = u1;
  }
  float hprev[2][2][4];
#pragma unroll
  for (int m = 0; m < 2; ++m)
#pragma unroll
    for (int j = 0; j < 4; ++j) {
      int b = b0 + m * 16 + kgrp * 4 + j;
      int rst = resets[s * BATCH + b];
      float h0 = 0.f, h1 = 0.f;
      if (useCarry && !rst) {
        h0 = carry[(size_t)b * HID + hid0];
        h1 = carry[(size_t)b * HID + hid0 + 16];
      }
      hprev[m][0][j] = h0; hprev[m][1][j] = h1;
    }

  const __half* gb = gi + (size_t)(s * 8 + bt) * BLKH + (unsigned)(wid * 64 + lane) * 48;
  float* opc = out + 65536 + ((size_t)s * BATCH + b0 + kgrp * 4) * HID + hid0;
  __syncthreads();

  // ---- pipelined scan: single-buffered gi (L2-resident), loads at step top
  for (int t = s; t < t1; ++t) {
    u16x8 gC[3][2];
#pragma unroll
    for (int g = 0; g < 3; ++g)
#pragma unroll
      for (int m = 0; m < 2; ++m)
        gC[g][m] = *(const u16x8*)(gb + g * 16 + m * 8);
    int tn = (t + 1 < T_LEN) ? t + 1 : T_LEN - 1;
    int4 rnC[2];
#pragma unroll
    for (int m = 0; m < 2; ++m)
      rnC[m] = *(const int4*)(resets + (size_t)tn * BATCH + b0 + m * 16 + kgrp * 4);

    const char* ab = Ald[(t - s) & 1];
    char* aw = (char*)Ald[((t - s) & 1) ^ 1];
    const bool lastT = (t + 1 >= T_LEN);

#pragma unroll
    for (int m = 0; m < 2; ++m) {
      fx4 aR0, aR1, aZ0, aZ1, aN0, aN1;
#pragma unroll
      for (int j = 0; j < 4; ++j) {
        aR0[j] = __half2float(__ushort_as_half(gC[0][m][j]));
        aR1[j] = __half2float(__ushort_as_half(gC[0][m][4 + j]));
        aZ0[j] = __half2float(__ushort_as_half(gC[1][m][j]));
        aZ1[j] = __half2float(__ushort_as_half(gC[1][m][4 + j]));
        aN0[j] = bhhn0;
        aN1[j] = bhhn1;
      }
#pragma unroll
      for (int s8 = 0; s8 < 8; ++s8) {
        unsigned aoff = ((unsigned)((m * 16 + col) * 512 + s8 * 64 + kgrp * 16)) ^
                        ((unsigned)(col & 7) << 4);
        s16x8 af  = *(const s16x8*)(ab + aoff);
        s16x8 wz1 = *(const s16x8*)(Wlds + (wid * 512 + s8 * 64 + lane) * 16);
        s16x8 wn1 = *(const s16x8*)(Wlds + 65536 + (wid * 512 + s8 * 64 + lane) * 16);
        aR0 = MFMA16(af, wrA[0][s8], aR0, 0, 0, 0);
        aR1 = MFMA16(af, wrA[1][s8], aR1, 0, 0, 0);
        aZ0 = MFMA16(af, wrA[2][s8], aZ0, 0, 0, 0);
        aZ1 = MFMA16(af, wz1, aZ1, 0, 0, 0);
        aN0 = MFMA16(af, wrA[3][s8], aN0, 0, 0, 0);
        aN1 = MFMA16(af, wn1, aN1, 0, 0, 0);
      }

      int4 rm = rnC[m];
#pragma unroll
      for (int j = 0; j < 4; ++j) {
        int b = m * 16 + kgrp * 4 + j;          // row within 32-b tile
        int rj = (j == 0) ? rm.x : (j == 1) ? rm.y : (j == 2) ? rm.z : rm.w;
        if (lastT) rj = 0;

        float r0 = __builtin_amdgcn_rcpf(1.f + __builtin_amdgcn_exp2f(-aR0[j]));
        float z0 = __builtin_amdgcn_rcpf(1.f + __builtin_amdgcn_exp2f(-aZ0[j]));
        float pn0 = __half2float(__ushort_as_half(gC[2][m][j])) + r0 * aN0[j];
        float n0 = 1.f - 2.f * __builtin_amdgcn_rcpf(1.f + __builtin_amdgcn_exp2f(pn0));
        float h0 = n0 + z0 * (hprev[m][0][j] - n0);

        float r1 = __builtin_amdgcn_rcpf(1.f + __builtin_amdgcn_exp2f(-aR1[j]));
        float z1 = __builtin_amdgcn_rcpf(1.f + __builtin_amdgcn_exp2f(-aZ1[j]));
        float pn1 = __half2float(__ushort_as_half(gC[2][m][4 + j])) + r1 * aN1[j];
        float n1 = 1.f - 2.f * __builtin_amdgcn_rcpf(1.f + __builtin_amdgcn_exp2f(pn1));
        float h1 = n1 + z1 * (hprev[m][1][j] - n1);

        __builtin_nontemporal_store(h0, opc + m * 4096 + j * HID);
        __builtin_nontemporal_store(h1, opc + m * 4096 + j * HID + 16);

        float hk0 = rj ? 0.f : h0;              // pre-apply reset[t+1]
        float hk1 = rj ? 0.f : h1;
        hprev[m][0][j] = hk0; hprev[m][1][j] = hk1;

        unsigned hw = cvt_pk_bf16(hk0, hk1);
        unsigned hoff = ((unsigned)(b * 512 + wid * 64 + col * 4)) ^
                        ((unsigned)(b & 7) << 4);
        *(unsigned*)(aw + hoff) = hw;
      }
    }

    gb += TSTRH;
    opc += 65536;
    soft_barrier();   // lgkm drain only; gi loads + out stores stay in flight
  }

  if (c == 31) {       // h_final = h after t=511 (reset guarded off)
#pragma unroll
    for (int m = 0; m < 2; ++m)
#pragma unroll
      for (int j = 0; j < 4; ++j) {
        int b = b0 + m * 16 + kgrp * 4 + j;
        out[(size_t)b * HID + hid0] = hprev[m][0][j];
        out[(size_t)b * HID + hid0 + 16] = hprev[m][1][j];
      }
  }
}

extern "C" void kernel_launch(void* const* d_in, const int* in_sizes, int n_in,
                              void* d_out, int out_size, void* d_ws, size_t ws_size,
                              hipStream_t stream) {
  const float* carry = (const float*)d_in[0];
  const float* X     = (const float*)d_in[1];
  const int*   rsts  = (const int*)d_in[2];
  const float* w_ih  = (const float*)d_in[3];
  const float* w_hh  = (const float*)d_in[4];
  const float* b_ih  = (const float*)d_in[5];
  const float* b_hh  = (const float*)d_in[6];
  float* out = (float*)d_out;

  const size_t gi_bytes = (size_t)T_LEN * BATCH * 3 * HID * sizeof(__half);  // 192 MiB
  if (ws_size < gi_bytes) return;
  __half* gi = (__half*)d_ws;

  gi_proj_kernel<<<256, 512, 0, stream>>>(X, w_ih, b_ih, b_hh, gi);
  gru_scan_kernel<<<256, 512, 0, stream>>>(carry, gi, rsts, w_hh, b_hh, out);
}